// Round 11
// baseline (457.231 us; speedup 1.0000x reference)
//
#include <hip/hip_runtime.h>
#include <math.h>

typedef __attribute__((ext_vector_type(8))) short bf16x8;
typedef __attribute__((ext_vector_type(4))) float f32x4;
typedef unsigned short u16;
typedef unsigned int u32;

#define NI    1152
#define DI    8
#define NO    10
#define DOUT  16
#define F     160
#define KTOT  9216
#define KS    288          // 32-wide k-steps across K=9216
#define SK    72           // split-K chunks in S-phase (4 ks = 128 k each)

// ws float offsets
#define OFF_SFH 0                    // 20480 f
#define OFF_SFL 20480
#define OFF_P   40960                // 72*40960 = 2949120 f
#define OFF_BA  2990080              // 11520
#define OFF_BB  3001600              // 11520
#define OFF_TP  3013120              // 4*11520 = 46080
#define OFF_CNT 3059200              // 8 ints (tile arrival counters)

union U8 { u16 u[8]; uint4 v; bf16x8 b; };

__device__ inline u16 bf16hi(float x) {
    u32 u = __float_as_uint(x);
    return (u16)((u + 0x7FFFu + ((u >> 16) & 1u)) >> 16);
}
__device__ inline float bf2f(u16 h) { return __uint_as_float(((u32)h) << 16); }

__device__ inline void split8(const float* v, bf16x8* bh, bf16x8* bl) {
    U8 h, l;
#pragma unroll
    for (int j = 0; j < 8; j++) {
        u16 hh = bf16hi(v[j]);
        h.u[j] = hh;
        l.u[j] = bf16hi(v[j] - bf2f(hh));
    }
    *bh = h.b; *bl = l.b;
}

// ---------------------------------------------------------------------------
// S-round with fused split-K reduction+squash (rs dispatch eliminated):
//  prologue: c = softmax(blog + sum_q tpart) for this block's 16 capsules
//  build c.W2 hi/lo B-frags in LDS (W gathered directly)
//  main: P[sk] partial via hi/lo bf16 MFMA (x loaded+split inline)
//  tail: RELEASE-arrive on tile counter; the 72nd block per (btg,fh) tile
//        ACQUIREs, reduces P over sk IN FIXED ORDER (bitwise == old rs),
//        squashes, emits s-frags (r<3) or final out (r==3).
// grid 576 = sk(72) x fh(2) x btg(4).
__global__ __launch_bounds__(256) void s_round(const float* __restrict__ x,
                                               const float* __restrict__ W,
                                               const float* __restrict__ tpart,
                                               const float* __restrict__ blogIn,
                                               float* __restrict__ blogOut,
                                               float* __restrict__ P,
                                               int* __restrict__ ctr,
                                               u16* __restrict__ sfh,
                                               u16* __restrict__ sfl,
                                               float* __restrict__ out, int r) {
    __shared__ __attribute__((aligned(16))) u16 cwhS[10240];   // [n*4+kk][512]
    __shared__ __attribute__((aligned(16))) u16 cwlS[10240];
    __shared__ float ts[16][NO];
    __shared__ float cls[16][NO];
    __shared__ int amLast;

    const int t = threadIdx.x, l = t & 63, w = t >> 6;
    const int bid = blockIdx.x;
    const int sk  = bid % SK;
    const int fh  = (bid / SK) & 1;
    const int btg = bid / (2 * SK);

    // --- prologue: routing coefficients for this block's 16 capsules ---
    if (r == 0) {
        if (t < 160) cls[t / NO][t % NO] = 0.1f;
    } else {
        if (t < 160) {
            int il = t / NO, o = t % NO;
            int ig = sk * 16 + il;
            float a = tpart[(size_t)ig * NO + o] +
                      tpart[(size_t)(NI + ig) * NO + o] +
                      tpart[(size_t)(2 * NI + ig) * NO + o] +
                      tpart[(size_t)(3 * NI + ig) * NO + o];
            float bnew = (r >= 2 ? blogIn[ig * NO + o] : 0.f) + a;
            blogOut[ig * NO + o] = bnew;      // duplicate identical write x8 blocks
            ts[il][o] = bnew;
        }
        __syncthreads();
        if (t < 16) {
            float m = -3.402823466e+38f;
#pragma unroll
            for (int o = 0; o < NO; o++) m = fmaxf(m, ts[t][o]);
            float e[NO];
            float sum = 0.f;
#pragma unroll
            for (int o = 0; o < NO; o++) { e[o] = expf(ts[t][o] - m); sum += e[o]; }
            float inv = 1.f / sum;
#pragma unroll
            for (int o = 0; o < NO; o++) cls[t][o] = e[o] * inv;
        }
    }
    __syncthreads();

    // --- build c.W2 hi/lo B-frags into LDS, gathering W directly ---
#pragma unroll
    for (int p = 0; p < 5; p++) {
        int vid  = p * 256 + t;      // 0..1279
        int frag = vid >> 6;         // n*4 + kk
        int ll   = vid & 63;
        int n = frag >> 2, kk = frag & 3;
        int ks = sk * 4 + kk;
        int o  = fh * 5 + n;
        int i  = ks * 4 + (ll >> 4), d = ll & 15;
        float cv = cls[kk * 4 + (ll >> 4)][o];
        const float* wp = W + ((size_t)(i * NO + o) * DOUT + d) * DI;
        float4 a = ((const float4*)wp)[0];
        float4 b = ((const float4*)wp)[1];
        float v[8] = {cv*a.x, cv*a.y, cv*a.z, cv*a.w, cv*b.x, cv*b.y, cv*b.z, cv*b.w};
        U8 ph, pl;
#pragma unroll
        for (int j = 0; j < 8; j++) {
            u16 h = bf16hi(v[j]);
            ph.u[j] = h; pl.u[j] = bf16hi(v[j] - bf2f(h));
        }
        *(uint4*)(cwhS + frag * 512 + ll * 8) = ph.v;
        *(uint4*)(cwlS + frag * 512 + ll * 8) = pl.v;
    }
    __syncthreads();

    // --- main MFMA: wave tile 16b x 80f over 128 k; x loaded+split inline ---
    const int bt = btg * 4 + w;
    f32x4 z = {0.f, 0.f, 0.f, 0.f};
    f32x4 acc[5];
#pragma unroll
    for (int n = 0; n < 5; n++) acc[n] = z;

#pragma unroll
    for (int kk = 0; kk < 4; kk++) {
        int ks = sk * 4 + kk;
        const float* xp = x + (size_t)(bt * 16 + (l & 15)) * KTOT + ks * 32 + (l >> 4) * 8;
        float4 a4 = ((const float4*)xp)[0];
        float4 b4 = ((const float4*)xp)[1];
        float v[8] = {a4.x, a4.y, a4.z, a4.w, b4.x, b4.y, b4.z, b4.w};
        bf16x8 ah, al;
        split8(v, &ah, &al);
#pragma unroll
        for (int n = 0; n < 5; n++) {
            bf16x8 bh = *(const bf16x8*)(cwhS + (n * 4 + kk) * 512 + l * 8);
            bf16x8 bl = *(const bf16x8*)(cwlS + (n * 4 + kk) * 512 + l * 8);
            acc[n] = __builtin_amdgcn_mfma_f32_16x16x32_bf16(ah, bh, acc[n], 0, 0, 0);
            acc[n] = __builtin_amdgcn_mfma_f32_16x16x32_bf16(ah, bl, acc[n], 0, 0, 0);
            acc[n] = __builtin_amdgcn_mfma_f32_16x16x32_bf16(al, bh, acc[n], 0, 0, 0);
        }
    }
    const int c0 = l & 15, rg = l >> 4;
    float* Pp = P + (size_t)sk * 40960 + (size_t)(bt * 16 + rg * 4) * F + fh * 80 + c0;
#pragma unroll
    for (int n = 0; n < 5; n++)
#pragma unroll
        for (int rr = 0; rr < 4; rr++)
            Pp[(size_t)rr * F + n * 16] = acc[n][rr];

    // --- tail: last-arriving block of this (btg,fh) tile reduces + squashes ---
    __syncthreads();   // all P stores of this block drained (vmcnt0+barrier)
    if (t == 0) {
        int old = __hip_atomic_fetch_add(ctr + (btg * 2 + fh), 1,
                                         __ATOMIC_RELEASE, __HIP_MEMORY_SCOPE_AGENT);
        amLast = (old == (r + 1) * SK - 1);
    }
    __syncthreads();
    if (!amLast) return;
    if (t == 0)
        __hip_atomic_load(ctr + (btg * 2 + fh), __ATOMIC_ACQUIRE, __HIP_MEMORY_SCOPE_AGENT);
    __syncthreads();   // block reads ordered behind the acquire

    const int b0 = btg * 64;
#pragma unroll 4
    for (int rep = 0; rep < 20; rep++) {
        int e  = rep * 256 + t;          // 0..5119
        int bl = e / 80, fl = e % 80;    // 16-lane group = one (b,o)'s 16 d's
        const float* pp = P + (size_t)(b0 + bl) * F + fh * 80 + fl;
        float sum = 0.f;
#pragma unroll 8
        for (int sk2 = 0; sk2 < SK; sk2++) sum += pp[(size_t)sk2 * 40960];
        float n2 = sum * sum;
#pragma unroll
        for (int off = 8; off > 0; off >>= 1) n2 += __shfl_xor(n2, off, 16);
        float l2v = sqrtf(n2);
        float scale = l2v / (1.f + n2);
        float sv = sum * scale;
        int b = b0 + bl, f = fh * 80 + fl;
        if (r == 3) {
            out[b * F + f] = sv;
        } else {
            size_t si = (size_t)((f >> 4) * 8 + (b >> 5)) * 512 +
                        (size_t)(((b >> 3) & 3) * 16 + (f & 15)) * 8 + (b & 7);
            u16 h = bf16hi(sv);
            sfh[si] = h;
            sfl[si] = bf16hi(sv - bf2f(h));
        }
    }
}

// ---------------------------------------------------------------------------
// Agreement: G = s^T x (partial over b-quarter) via MFMA -> LDS ->
// contract with W -> tpart[bq][i][o] (=, full overwrite). x^T frags split inline.
// grid 576 = nb(144) x bq(4).
__global__ __launch_bounds__(256) void c1(const u16* __restrict__ sfh,
                                          const u16* __restrict__ sfl,
                                          const float* __restrict__ x,
                                          const float* __restrict__ W,
                                          float* __restrict__ tpart) {
    __shared__ __attribute__((aligned(16))) float G[160 * 68];
    const int t = threadIdx.x, l = t & 63, w = t >> 6;
    const int nb = blockIdx.x >> 2, bq = blockIdx.x & 3;
    const int wm = w & 1, wn = w >> 1;

    f32x4 z = {0.f, 0.f, 0.f, 0.f};
    f32x4 acc[5][2];
#pragma unroll
    for (int m = 0; m < 5; m++)
#pragma unroll
        for (int n = 0; n < 2; n++) acc[m][n] = z;

#pragma unroll
    for (int ksl = 0; ksl < 2; ksl++) {
        int ksb = bq * 2 + ksl;
        bf16x8 ah[5], al[5];
#pragma unroll
        for (int m = 0; m < 5; m++) {
            size_t ai = ((size_t)((wm * 5 + m) * 8 + ksb)) * 512 + l * 8;
            ah[m] = *(const bf16x8*)(sfh + ai);
            al[m] = *(const bf16x8*)(sfl + ai);
        }
#pragma unroll
        for (int nl = 0; nl < 2; nl++) {
            int ns = nb * 4 + wn * 2 + nl;
            const float* xp = x + (size_t)(ksb * 32 + (l >> 4) * 8) * KTOT + ns * 16 + (l & 15);
            float v[8];
#pragma unroll
            for (int j = 0; j < 8; j++) v[j] = xp[(size_t)j * KTOT];
            bf16x8 bh, blo;
            split8(v, &bh, &blo);
#pragma unroll
            for (int m = 0; m < 5; m++) {
                acc[m][nl] = __builtin_amdgcn_mfma_f32_16x16x32_bf16(ah[m], bh, acc[m][nl], 0, 0, 0);
                acc[m][nl] = __builtin_amdgcn_mfma_f32_16x16x32_bf16(ah[m], blo, acc[m][nl], 0, 0, 0);
                acc[m][nl] = __builtin_amdgcn_mfma_f32_16x16x32_bf16(al[m], bh, acc[m][nl], 0, 0, 0);
            }
        }
    }
    const int c0 = l & 15, rg = l >> 4;
#pragma unroll
    for (int m = 0; m < 5; m++)
#pragma unroll
        for (int nl = 0; nl < 2; nl++)
#pragma unroll
            for (int rr = 0; rr < 4; rr++)
                G[(wm * 80 + m * 16 + rg * 4 + rr) * 68 + wn * 32 + nl * 16 + c0] = acc[m][nl][rr];
    __syncthreads();
    if (t < 160) {
        int i_l = t / 20, o = (t % 20) >> 1, dh = t & 1;
        int i_g = nb * 8 + i_l;
        const float* wp = W + (size_t)(i_g * NO + o) * 128 + dh * 64;
        float sum = 0.f;
#pragma unroll
        for (int d = 0; d < 8; d++) {
            const float* gp = &G[(o * 16 + dh * 8 + d) * 68 + i_l * 8];
            float4 g0 = ((const float4*)gp)[0], g1 = ((const float4*)gp)[1];
            float4 w0 = ((const float4*)(wp + d * 8))[0], w1 = ((const float4*)(wp + d * 8))[1];
            sum += g0.x * w0.x + g0.y * w0.y + g0.z * w0.z + g0.w * w0.w +
                   g1.x * w1.x + g1.y * w1.y + g1.z * w1.z + g1.w * w1.w;
        }
        sum += __shfl_xor(sum, 1);
        if (dh == 0) tpart[(size_t)(bq * NI + i_g) * NO + o] = sum;
    }
}

// ---------------------------------------------------------------------------
extern "C" void kernel_launch(void* const* d_in, const int* in_sizes, int n_in,
                              void* d_out, int out_size, void* d_ws, size_t ws_size,
                              hipStream_t stream) {
    const float* x = (const float*)d_in[0];
    const float* W = (const float*)d_in[1];
    float* out = (float*)d_out;
    float* ws  = (float*)d_ws;
    u16* sfh = (u16*)(ws + OFF_SFH);
    u16* sfl = (u16*)(ws + OFF_SFL);
    float* P   = ws + OFF_P;
    float* blA = ws + OFF_BA;
    float* blB = ws + OFF_BB;
    float* tp  = ws + OFF_TP;
    int* ctr   = (int*)(ws + OFF_CNT);

    hipMemsetAsync(ctr, 0, 8 * sizeof(int), stream);

    for (int r = 0; r < 4; r++) {
        // r1: blog=0+t -> blB; r2: blB+t -> blA; r3: blA+t -> blB
        const float* bIn = (r == 2) ? blB : blA;
        float* bOut      = (r == 2) ? blA : blB;
        s_round<<<576, 256, 0, stream>>>(x, W, tp, bIn, bOut, P, ctr, sfh, sfl, out, r);
        if (r < 3)
            c1<<<576, 256, 0, stream>>>(sfh, sfl, x, W, tp);
    }
}

// Round 12
// 104.155 us; speedup vs baseline: 4.3899x; 4.3899x over previous
//
#include <hip/hip_runtime.h>
#include <math.h>

typedef __attribute__((ext_vector_type(8))) short bf16x8;
typedef __attribute__((ext_vector_type(4))) float f32x4;
typedef unsigned short u16;
typedef unsigned int u32;

#define NI    1152
#define DI    8
#define NO    10
#define DOUT  16
#define F     160
#define KTOT  9216
#define KS    288          // 32-wide k-steps across K=9216
#define SK    36           // split-K chunks in S-phase (8 ks = 256 k each)

// ws float offsets
#define OFF_SFH 0                    // 20480 f
#define OFF_SFL 20480
#define OFF_P   40960                // 36*40960 = 1474560 f
#define OFF_BA  1515520              // 11520
#define OFF_BB  1527040              // 11520
#define OFF_TP  1538560              // 4*11520 = 46080

union U8 { u16 u[8]; uint4 v; bf16x8 b; };

__device__ inline u16 bf16hi(float x) {
    u32 u = __float_as_uint(x);
    return (u16)((u + 0x7FFFu + ((u >> 16) & 1u)) >> 16);
}
__device__ inline float bf2f(u16 h) { return __uint_as_float(((u32)h) << 16); }

__device__ inline void split8(const float* v, bf16x8* bh, bf16x8* bl) {
    U8 h, l;
#pragma unroll
    for (int j = 0; j < 8; j++) {
        u16 hh = bf16hi(v[j]);
        h.u[j] = hh;
        l.u[j] = bf16hi(v[j] - bf2f(hh));
    }
    *bh = h.b; *bl = l.b;
}

// ---------------------------------------------------------------------------
// S-round (SK=36): prologue softmax for this block's 32 capsules; two LDS
// frag-build passes (kt=0,1) of c.W2 hi/lo; 8 ks of hi/lo MFMA; P written
// with NON-TEMPORAL stores (L2 bypass -> tiny dispatch-boundary flush).
// grid 288 = sk(36) x fh(2) x btg(4).
__global__ __launch_bounds__(256) void s_round(const float* __restrict__ x,
                                               const float* __restrict__ W,
                                               const float* __restrict__ tpart,
                                               const float* __restrict__ blogIn,
                                               float* __restrict__ blogOut,
                                               float* __restrict__ P, int r) {
    __shared__ __attribute__((aligned(16))) u16 cwhS[10240];   // [n*4+kkl][512]
    __shared__ __attribute__((aligned(16))) u16 cwlS[10240];
    __shared__ float ts[32][NO];
    __shared__ float cls[32][NO];

    const int t = threadIdx.x, l = t & 63, w = t >> 6;
    const int bid = blockIdx.x;
    const int sk  = bid % SK;
    const int fh  = (bid / SK) & 1;
    const int btg = bid / (2 * SK);

    // --- prologue: routing coefficients for this block's 32 capsules ---
    if (r == 0) {
        for (int e = t; e < 320; e += 256) cls[e / NO][e % NO] = 0.1f;
    } else {
        for (int e = t; e < 320; e += 256) {
            int il = e / NO, o = e % NO;
            int ig = sk * 32 + il;
            float a = tpart[(size_t)ig * NO + o] +
                      tpart[(size_t)(NI + ig) * NO + o] +
                      tpart[(size_t)(2 * NI + ig) * NO + o] +
                      tpart[(size_t)(3 * NI + ig) * NO + o];
            float bnew = (r >= 2 ? blogIn[ig * NO + o] : 0.f) + a;
            if (r < 3) blogOut[ig * NO + o] = bnew;   // identical dup write x8
            ts[il][o] = bnew;
        }
        __syncthreads();
        if (t < 32) {
            float m = -3.402823466e+38f;
#pragma unroll
            for (int o = 0; o < NO; o++) m = fmaxf(m, ts[t][o]);
            float e[NO];
            float sum = 0.f;
#pragma unroll
            for (int o = 0; o < NO; o++) { e[o] = expf(ts[t][o] - m); sum += e[o]; }
            float inv = 1.f / sum;
#pragma unroll
            for (int o = 0; o < NO; o++) cls[t][o] = e[o] * inv;
        }
    }

    const int bt = btg * 4 + w;
    f32x4 z = {0.f, 0.f, 0.f, 0.f};
    f32x4 acc[5];
#pragma unroll
    for (int n = 0; n < 5; n++) acc[n] = z;

#pragma unroll
    for (int kt = 0; kt < 2; kt++) {
        __syncthreads();   // frag LDS safe to overwrite / cls ready
        // --- build c.W2 hi/lo frags for kkl = kt*4..+3 ---
#pragma unroll
        for (int p = 0; p < 5; p++) {
            int vid  = p * 256 + t;      // 0..1279
            int frag = vid >> 6;         // n*4 + kkl
            int ll   = vid & 63;
            int n = frag >> 2, kkl = frag & 3;
            int ksl = kt * 4 + kkl;              // 0..7
            int ks  = sk * 8 + ksl;
            int o   = fh * 5 + n;
            int i   = ks * 4 + (ll >> 4), d = ll & 15;
            float cv = cls[ksl * 4 + (ll >> 4)][o];
            const float* wp = W + ((size_t)(i * NO + o) * DOUT + d) * DI;
            float4 a = ((const float4*)wp)[0];
            float4 b = ((const float4*)wp)[1];
            float v[8] = {cv*a.x, cv*a.y, cv*a.z, cv*a.w, cv*b.x, cv*b.y, cv*b.z, cv*b.w};
            U8 ph, pl;
#pragma unroll
            for (int j = 0; j < 8; j++) {
                u16 h = bf16hi(v[j]);
                ph.u[j] = h; pl.u[j] = bf16hi(v[j] - bf2f(h));
            }
            *(uint4*)(cwhS + frag * 512 + ll * 8) = ph.v;
            *(uint4*)(cwlS + frag * 512 + ll * 8) = pl.v;
        }
        __syncthreads();
        // --- 4 ks of MFMA; x loaded+split inline ---
#pragma unroll
        for (int kkl = 0; kkl < 4; kkl++) {
            int ks = sk * 8 + kt * 4 + kkl;
            const float* xp = x + (size_t)(bt * 16 + (l & 15)) * KTOT + ks * 32 + (l >> 4) * 8;
            float4 a4 = ((const float4*)xp)[0];
            float4 b4 = ((const float4*)xp)[1];
            float v[8] = {a4.x, a4.y, a4.z, a4.w, b4.x, b4.y, b4.z, b4.w};
            bf16x8 ah, al;
            split8(v, &ah, &al);
#pragma unroll
            for (int n = 0; n < 5; n++) {
                bf16x8 bh = *(const bf16x8*)(cwhS + (n * 4 + kkl) * 512 + l * 8);
                bf16x8 bl = *(const bf16x8*)(cwlS + (n * 4 + kkl) * 512 + l * 8);
                acc[n] = __builtin_amdgcn_mfma_f32_16x16x32_bf16(ah, bh, acc[n], 0, 0, 0);
                acc[n] = __builtin_amdgcn_mfma_f32_16x16x32_bf16(ah, bl, acc[n], 0, 0, 0);
                acc[n] = __builtin_amdgcn_mfma_f32_16x16x32_bf16(al, bh, acc[n], 0, 0, 0);
            }
        }
    }
    const int c0 = l & 15, rg = l >> 4;
    float* Pp = P + (size_t)sk * 40960 + (size_t)(bt * 16 + rg * 4) * F + fh * 80 + c0;
#pragma unroll
    for (int n = 0; n < 5; n++)
#pragma unroll
        for (int rr = 0; rr < 4; rr++)
            __builtin_nontemporal_store(acc[n][rr], Pp + (size_t)rr * F + n * 16);
}

// ---------------------------------------------------------------------------
// s = squash(sum_sk P) with NT P-loads; last round -> fp32 out, else s-frags
__global__ void rs(const float* __restrict__ P, float* __restrict__ sout,
                   u16* __restrict__ sfh, u16* __restrict__ sfl, int last) {
    int idx = blockIdx.x * 256 + threadIdx.x;   // b*160 + f
    const float* pp = P + idx;
    float sum = 0.f;
#pragma unroll 6
    for (int sk2 = 0; sk2 < SK; sk2++)
        sum += __builtin_nontemporal_load(pp + (size_t)sk2 * 40960);
    float n2 = sum * sum;
#pragma unroll
    for (int off = 8; off > 0; off >>= 1) n2 += __shfl_xor(n2, off, 16);
    float l2v = sqrtf(n2);
    float scale = l2v / (1.f + n2);
    float sv = sum * scale;
    if (last) {
        sout[idx] = sv;
    } else {
        int b = idx / F, f = idx % F;
        size_t si = (size_t)((f >> 4) * 8 + (b >> 5)) * 512 +
                    (size_t)(((b >> 3) & 3) * 16 + (f & 15)) * 8 + (b & 7);
        u16 h = bf16hi(sv);
        sfh[si] = h;
        sfl[si] = bf16hi(sv - bf2f(h));
    }
}

// ---------------------------------------------------------------------------
// Agreement: G = s^T x (partial over b-quarter) via MFMA -> LDS ->
// contract with W -> tpart[bq][i][o] (=, full overwrite). x^T frags split inline.
// grid 576 = nb(144) x bq(4).
__global__ __launch_bounds__(256) void c1(const u16* __restrict__ sfh,
                                          const u16* __restrict__ sfl,
                                          const float* __restrict__ x,
                                          const float* __restrict__ W,
                                          float* __restrict__ tpart) {
    __shared__ __attribute__((aligned(16))) float G[160 * 68];
    const int t = threadIdx.x, l = t & 63, w = t >> 6;
    const int nb = blockIdx.x >> 2, bq = blockIdx.x & 3;
    const int wm = w & 1, wn = w >> 1;

    f32x4 z = {0.f, 0.f, 0.f, 0.f};
    f32x4 acc[5][2];
#pragma unroll
    for (int m = 0; m < 5; m++)
#pragma unroll
        for (int n = 0; n < 2; n++) acc[m][n] = z;

#pragma unroll
    for (int ksl = 0; ksl < 2; ksl++) {
        int ksb = bq * 2 + ksl;
        bf16x8 ah[5], al[5];
#pragma unroll
        for (int m = 0; m < 5; m++) {
            size_t ai = ((size_t)((wm * 5 + m) * 8 + ksb)) * 512 + l * 8;
            ah[m] = *(const bf16x8*)(sfh + ai);
            al[m] = *(const bf16x8*)(sfl + ai);
        }
#pragma unroll
        for (int nl = 0; nl < 2; nl++) {
            int ns = nb * 4 + wn * 2 + nl;
            const float* xp = x + (size_t)(ksb * 32 + (l >> 4) * 8) * KTOT + ns * 16 + (l & 15);
            float v[8];
#pragma unroll
            for (int j = 0; j < 8; j++) v[j] = xp[(size_t)j * KTOT];
            bf16x8 bh, blo;
            split8(v, &bh, &blo);
#pragma unroll
            for (int m = 0; m < 5; m++) {
                acc[m][nl] = __builtin_amdgcn_mfma_f32_16x16x32_bf16(ah[m], bh, acc[m][nl], 0, 0, 0);
                acc[m][nl] = __builtin_amdgcn_mfma_f32_16x16x32_bf16(ah[m], blo, acc[m][nl], 0, 0, 0);
                acc[m][nl] = __builtin_amdgcn_mfma_f32_16x16x32_bf16(al[m], bh, acc[m][nl], 0, 0, 0);
            }
        }
    }
    const int c0 = l & 15, rg = l >> 4;
#pragma unroll
    for (int m = 0; m < 5; m++)
#pragma unroll
        for (int nl = 0; nl < 2; nl++)
#pragma unroll
            for (int rr = 0; rr < 4; rr++)
                G[(wm * 80 + m * 16 + rg * 4 + rr) * 68 + wn * 32 + nl * 16 + c0] = acc[m][nl][rr];
    __syncthreads();
    if (t < 160) {
        int i_l = t / 20, o = (t % 20) >> 1, dh = t & 1;
        int i_g = nb * 8 + i_l;
        const float* wp = W + (size_t)(i_g * NO + o) * 128 + dh * 64;
        float sum = 0.f;
#pragma unroll
        for (int d = 0; d < 8; d++) {
            const float* gp = &G[(o * 16 + dh * 8 + d) * 68 + i_l * 8];
            float4 g0 = ((const float4*)gp)[0], g1 = ((const float4*)gp)[1];
            float4 w0 = ((const float4*)(wp + d * 8))[0], w1 = ((const float4*)(wp + d * 8))[1];
            sum += g0.x * w0.x + g0.y * w0.y + g0.z * w0.z + g0.w * w0.w +
                   g1.x * w1.x + g1.y * w1.y + g1.z * w1.z + g1.w * w1.w;
        }
        sum += __shfl_xor(sum, 1);
        if (dh == 0) tpart[(size_t)(bq * NI + i_g) * NO + o] = sum;
    }
}

// ---------------------------------------------------------------------------
extern "C" void kernel_launch(void* const* d_in, const int* in_sizes, int n_in,
                              void* d_out, int out_size, void* d_ws, size_t ws_size,
                              hipStream_t stream) {
    const float* x = (const float*)d_in[0];
    const float* W = (const float*)d_in[1];
    float* out = (float*)d_out;
    float* ws  = (float*)d_ws;
    u16* sfh = (u16*)(ws + OFF_SFH);
    u16* sfl = (u16*)(ws + OFF_SFL);
    float* P   = ws + OFF_P;
    float* blA = ws + OFF_BA;
    float* blB = ws + OFF_BB;
    float* tp  = ws + OFF_TP;

    for (int r = 0; r < 4; r++) {
        // r1: blog=0+t -> blB; r2: blB+t -> blA; r3: blA+t (no write)
        const float* bIn = (r == 2) ? blB : blA;
        float* bOut      = (r == 2) ? blA : blB;
        s_round<<<288, 256, 0, stream>>>(x, W, tp, bIn, bOut, P, r);
        rs<<<160, 256, 0, stream>>>(P, out, sfh, sfl, r == 3 ? 1 : 0);
        if (r < 3)
            c1<<<576, 256, 0, stream>>>(sfh, sfl, x, W, tp);
    }
}

// Round 13
// 98.072 us; speedup vs baseline: 4.6622x; 1.0620x over previous
//
#include <hip/hip_runtime.h>
#include <math.h>

typedef __attribute__((ext_vector_type(8))) short bf16x8;
typedef __attribute__((ext_vector_type(4))) float f32x4;
typedef unsigned short u16;
typedef unsigned int u32;

#define NI    1152
#define DI    8
#define NO    10
#define DOUT  16
#define F     160
#define KTOT  9216
#define KS    288          // 32-wide k-steps across K=9216
#define SK    72           // split-K chunks in S-phase (4 ks = 128 k each)

// ws float offsets (12.2 MB total)
#define OFF_SFH 0                    // 20480 f
#define OFF_SFL 20480
#define OFF_P   40960                // 72*40960 = 2949120 f
#define OFF_BA  2990080              // 11520
#define OFF_BB  3001600              // 11520
#define OFF_TP  3013120              // 4*11520 = 46080

union U8 { u16 u[8]; uint4 v; bf16x8 b; };

__device__ inline u16 bf16hi(float x) {
    u32 u = __float_as_uint(x);
    return (u16)((u + 0x7FFFu + ((u >> 16) & 1u)) >> 16);
}
__device__ inline float bf2f(u16 h) { return __uint_as_float(((u32)h) << 16); }

__device__ inline void split8(const float* v, bf16x8* bh, bf16x8* bl) {
    U8 h, l;
#pragma unroll
    for (int j = 0; j < 8; j++) {
        u16 hh = bf16hi(v[j]);
        h.u[j] = hh;
        l.u[j] = bf16hi(v[j] - bf2f(hh));
    }
    *bh = h.b; *bl = l.b;
}

// ---------------------------------------------------------------------------
// S-round, fully self-contained:
//  prologue: c = softmax(blog + sum_q tpart) for this block's 16 capsules
//  split c.W2 hi/lo B-frags into LDS (W gathered directly)
//  main: P[sk][b][f] partials via hi/lo bf16 MFMA, x loaded+split inline
// grid 576 = sk(72) x fh(2) x btg(4); mode: 0=r0 (c=0.1), 1=r1 (blogIn=0), 2=else
__global__ __launch_bounds__(256) void s_round(const float* __restrict__ x,
                                               const float* __restrict__ W,
                                               const float* __restrict__ tpart,
                                               const float* __restrict__ blogIn,
                                               float* __restrict__ blogOut,
                                               float* __restrict__ P, int mode) {
    __shared__ __attribute__((aligned(16))) u16 cwhS[10240];   // [n*4+kk][512]
    __shared__ __attribute__((aligned(16))) u16 cwlS[10240];
    __shared__ float ts[16][NO];
    __shared__ float cls[16][NO];

    const int t = threadIdx.x, l = t & 63, w = t >> 6;
    const int bid = blockIdx.x;
    const int sk  = bid % SK;
    const int fh  = (bid / SK) & 1;
    const int btg = bid / (2 * SK);

    // --- prologue: routing coefficients for this block's 16 capsules ---
    if (mode == 0) {
        if (t < 160) cls[t / NO][t % NO] = 0.1f;
    } else {
        if (t < 160) {
            int il = t / NO, o = t % NO;
            int ig = sk * 16 + il;
            float a = tpart[(size_t)ig * NO + o] +
                      tpart[(size_t)(NI + ig) * NO + o] +
                      tpart[(size_t)(2 * NI + ig) * NO + o] +
                      tpart[(size_t)(3 * NI + ig) * NO + o];
            float bnew = (mode == 2 ? blogIn[ig * NO + o] : 0.f) + a;
            blogOut[ig * NO + o] = bnew;      // duplicate identical write x8 blocks
            ts[il][o] = bnew;
        }
        __syncthreads();
        if (t < 16) {
            float m = -3.402823466e+38f;
#pragma unroll
            for (int o = 0; o < NO; o++) m = fmaxf(m, ts[t][o]);
            float e[NO];
            float sum = 0.f;
#pragma unroll
            for (int o = 0; o < NO; o++) { e[o] = expf(ts[t][o] - m); sum += e[o]; }
            float inv = 1.f / sum;
#pragma unroll
            for (int o = 0; o < NO; o++) cls[t][o] = e[o] * inv;
        }
    }
    __syncthreads();

    // --- build c.W2 hi/lo B-frags into LDS, gathering W directly ---
#pragma unroll
    for (int p = 0; p < 5; p++) {
        int vid  = p * 256 + t;      // 0..1279
        int frag = vid >> 6;         // n*4 + kk
        int ll   = vid & 63;
        int n = frag >> 2, kk = frag & 3;
        int ks = sk * 4 + kk;
        int o  = fh * 5 + n;
        int i  = ks * 4 + (ll >> 4), d = ll & 15;
        float cv = cls[kk * 4 + (ll >> 4)][o];
        const float* wp = W + ((size_t)(i * NO + o) * DOUT + d) * DI;
        float4 a = ((const float4*)wp)[0];
        float4 b = ((const float4*)wp)[1];
        float v[8] = {cv*a.x, cv*a.y, cv*a.z, cv*a.w, cv*b.x, cv*b.y, cv*b.z, cv*b.w};
        U8 ph, pl;
#pragma unroll
        for (int j = 0; j < 8; j++) {
            u16 h = bf16hi(v[j]);
            ph.u[j] = h; pl.u[j] = bf16hi(v[j] - bf2f(h));
        }
        *(uint4*)(cwhS + frag * 512 + ll * 8) = ph.v;
        *(uint4*)(cwlS + frag * 512 + ll * 8) = pl.v;
    }
    __syncthreads();

    // --- main MFMA: wave tile 16b x 80f over 128 k; x loaded+split inline ---
    const int bt = btg * 4 + w;
    f32x4 z = {0.f, 0.f, 0.f, 0.f};
    f32x4 acc[5];
#pragma unroll
    for (int n = 0; n < 5; n++) acc[n] = z;

#pragma unroll
    for (int kk = 0; kk < 4; kk++) {
        int ks = sk * 4 + kk;
        const float* xp = x + (size_t)(bt * 16 + (l & 15)) * KTOT + ks * 32 + (l >> 4) * 8;
        float4 a4 = ((const float4*)xp)[0];
        float4 b4 = ((const float4*)xp)[1];
        float v[8] = {a4.x, a4.y, a4.z, a4.w, b4.x, b4.y, b4.z, b4.w};
        bf16x8 ah, al;
        split8(v, &ah, &al);
#pragma unroll
        for (int n = 0; n < 5; n++) {
            bf16x8 bh = *(const bf16x8*)(cwhS + (n * 4 + kk) * 512 + l * 8);
            bf16x8 bl = *(const bf16x8*)(cwlS + (n * 4 + kk) * 512 + l * 8);
            acc[n] = __builtin_amdgcn_mfma_f32_16x16x32_bf16(ah, bh, acc[n], 0, 0, 0);
            acc[n] = __builtin_amdgcn_mfma_f32_16x16x32_bf16(ah, bl, acc[n], 0, 0, 0);
            acc[n] = __builtin_amdgcn_mfma_f32_16x16x32_bf16(al, bh, acc[n], 0, 0, 0);
        }
    }
    const int c0 = l & 15, rg = l >> 4;
    float* Pp = P + (size_t)sk * 40960 + (size_t)(bt * 16 + rg * 4) * F + fh * 80 + c0;
#pragma unroll
    for (int n = 0; n < 5; n++)
#pragma unroll
        for (int rr = 0; rr < 4; rr++)
            Pp[(size_t)rr * F + n * 16] = acc[n][rr];
}

// ---------------------------------------------------------------------------
// s = squash(sum_sk P); last round -> fp32 out, else hi/lo A-frags for c1
__global__ void rs(const float* __restrict__ P, float* __restrict__ sout,
                   u16* __restrict__ sfh, u16* __restrict__ sfl, int last) {
    int idx = blockIdx.x * 256 + threadIdx.x;   // b*160 + f
    float sum = 0.f;
#pragma unroll 8
    for (int sk2 = 0; sk2 < SK; sk2++) sum += P[(size_t)sk2 * 40960 + idx];
    float n2 = sum * sum;
#pragma unroll
    for (int off = 8; off > 0; off >>= 1) n2 += __shfl_xor(n2, off, 16);
    float l2v = sqrtf(n2);
    float scale = l2v / (1.f + n2);
    float sv = sum * scale;
    if (last) {
        sout[idx] = sv;
    } else {
        int b = idx / F, f = idx % F;
        size_t si = (size_t)((f >> 4) * 8 + (b >> 5)) * 512 +
                    (size_t)(((b >> 3) & 3) * 16 + (f & 15)) * 8 + (b & 7);
        u16 h = bf16hi(sv);
        sfh[si] = h;
        sfl[si] = bf16hi(sv - bf2f(h));
    }
}

// ---------------------------------------------------------------------------
// Agreement: G = s^T x (partial over b-quarter) via MFMA -> LDS ->
// contract with W -> tpart[bq][i][o] (=, full overwrite). x^T frags split inline.
// grid 576 = nb(144) x bq(4).
__global__ __launch_bounds__(256) void c1(const u16* __restrict__ sfh,
                                          const u16* __restrict__ sfl,
                                          const float* __restrict__ x,
                                          const float* __restrict__ W,
                                          float* __restrict__ tpart) {
    __shared__ __attribute__((aligned(16))) float G[160 * 68];
    const int t = threadIdx.x, l = t & 63, w = t >> 6;
    const int nb = blockIdx.x >> 2, bq = blockIdx.x & 3;
    const int wm = w & 1, wn = w >> 1;

    f32x4 z = {0.f, 0.f, 0.f, 0.f};
    f32x4 acc[5][2];
#pragma unroll
    for (int m = 0; m < 5; m++)
#pragma unroll
        for (int n = 0; n < 2; n++) acc[m][n] = z;

#pragma unroll
    for (int ksl = 0; ksl < 2; ksl++) {
        int ksb = bq * 2 + ksl;
        bf16x8 ah[5], al[5];
#pragma unroll
        for (int m = 0; m < 5; m++) {
            size_t ai = ((size_t)((wm * 5 + m) * 8 + ksb)) * 512 + l * 8;
            ah[m] = *(const bf16x8*)(sfh + ai);
            al[m] = *(const bf16x8*)(sfl + ai);
        }
#pragma unroll
        for (int nl = 0; nl < 2; nl++) {
            int ns = nb * 4 + wn * 2 + nl;
            const float* xp = x + (size_t)(ksb * 32 + (l >> 4) * 8) * KTOT + ns * 16 + (l & 15);
            float v[8];
#pragma unroll
            for (int j = 0; j < 8; j++) v[j] = xp[(size_t)j * KTOT];
            bf16x8 bh, blo;
            split8(v, &bh, &blo);
#pragma unroll
            for (int m = 0; m < 5; m++) {
                acc[m][nl] = __builtin_amdgcn_mfma_f32_16x16x32_bf16(ah[m], bh, acc[m][nl], 0, 0, 0);
                acc[m][nl] = __builtin_amdgcn_mfma_f32_16x16x32_bf16(ah[m], blo, acc[m][nl], 0, 0, 0);
                acc[m][nl] = __builtin_amdgcn_mfma_f32_16x16x32_bf16(al[m], bh, acc[m][nl], 0, 0, 0);
            }
        }
    }
    const int c0 = l & 15, rg = l >> 4;
#pragma unroll
    for (int m = 0; m < 5; m++)
#pragma unroll
        for (int nl = 0; nl < 2; nl++)
#pragma unroll
            for (int rr = 0; rr < 4; rr++)
                G[(wm * 80 + m * 16 + rg * 4 + rr) * 68 + wn * 32 + nl * 16 + c0] = acc[m][nl][rr];
    __syncthreads();
    if (t < 160) {
        int i_l = t / 20, o = (t % 20) >> 1, dh = t & 1;
        int i_g = nb * 8 + i_l;
        const float* wp = W + (size_t)(i_g * NO + o) * 128 + dh * 64;
        float sum = 0.f;
#pragma unroll
        for (int d = 0; d < 8; d++) {
            const float* gp = &G[(o * 16 + dh * 8 + d) * 68 + i_l * 8];
            float4 g0 = ((const float4*)gp)[0], g1 = ((const float4*)gp)[1];
            float4 w0 = ((const float4*)(wp + d * 8))[0], w1 = ((const float4*)(wp + d * 8))[1];
            sum += g0.x * w0.x + g0.y * w0.y + g0.z * w0.z + g0.w * w0.w +
                   g1.x * w1.x + g1.y * w1.y + g1.z * w1.z + g1.w * w1.w;
        }
        sum += __shfl_xor(sum, 1);
        if (dh == 0) tpart[(size_t)(bq * NI + i_g) * NO + o] = sum;
    }
}

// ---------------------------------------------------------------------------
extern "C" void kernel_launch(void* const* d_in, const int* in_sizes, int n_in,
                              void* d_out, int out_size, void* d_ws, size_t ws_size,
                              hipStream_t stream) {
    const float* x = (const float*)d_in[0];
    const float* W = (const float*)d_in[1];
    float* out = (float*)d_out;
    float* ws  = (float*)d_ws;
    u16* sfh = (u16*)(ws + OFF_SFH);
    u16* sfl = (u16*)(ws + OFF_SFL);
    float* P   = ws + OFF_P;
    float* blA = ws + OFF_BA;
    float* blB = ws + OFF_BB;
    float* tp  = ws + OFF_TP;

    for (int r = 0; r < 4; r++) {
        // r1: blog=0+t -> blB; r2: blB+t -> blA; r3: blA+t -> blB
        int mode = (r == 0) ? 0 : (r == 1 ? 1 : 2);
        const float* bIn = (r == 2) ? blB : blA;
        float* bOut      = (r == 2) ? blA : blB;
        s_round<<<576, 256, 0, stream>>>(x, W, tp, bIn, bOut, P, mode);
        rs<<<160, 256, 0, stream>>>(P, out, sfh, sfl, r == 3 ? 1 : 0);
        if (r < 3)
            c1<<<576, 256, 0, stream>>>(sfh, sfl, x, W, tp);
    }
}